// Round 1
// baseline (108.934 us; speedup 1.0000x reference)
//
#include <hip/hip_runtime.h>

#define BB 2
#define LL 24
#define RR 8
#define CC 32
#define HH 48
#define WF 49
#define HW (HH*WF)            // 2352
#define ASLAB (RR*CC*WF)      // 12544  (A elements per (b,l))
#define SLAB (RR*CC*HH*WF)    // 602112 (u elements per (b,l))
#define OUT_HALF (BB*LL*SLAB) // 28901376
#define NCH (BB*SLAB)         // 1204224 independent chains
#define NTHREADS (NCH/4)      // 301056 (each thread owns 4 consecutive chains)

__global__ __launch_bounds__(256) void a_kernel(const float* __restrict__ nu,
                                                const float* __restrict__ th,
                                                const float* __restrict__ dts,
                                                float* __restrict__ Ar,
                                                float* __restrict__ Ai) {
    int i = blockIdx.x * 256 + threadIdx.x;
    if (i >= BB * LL * ASLAB) return;
    int bl = i / ASLAB;             // b*L + l
    float dt = dts[bl];
    float decay = expf(-nu[i] * dt);
    float s, c;
    sincosf(th[i] * dt, &s, &c);
    Ar[i] = decay * c;
    Ai[i] = decay * s;
}

template<bool PRE>
__global__ __launch_bounds__(256) void scan_kernel(const float* __restrict__ ur,
                                                   const float* __restrict__ ui,
                                                   const float* __restrict__ Ar,
                                                   const float* __restrict__ Ai,
                                                   const float* __restrict__ nu,
                                                   const float* __restrict__ th,
                                                   const float* __restrict__ dts,
                                                   float* __restrict__ out) {
    int t = blockIdx.x * 256 + threadIdx.x;   // 0 .. NTHREADS-1 (exact grid)
    int c4 = t * 4;                           // first of 4 consecutive chains
    int b = c4 / SLAB;
    int rest = c4 - b * SLAB;                 // multiple of 4, < SLAB
    int rc = rest / HW;                       // r*C + c   (A group)
    int hw = rest - rc * HW;                  // h*WF + w; hw+3 < HW since HW%4==0
    int w0 = hw % WF;

    int a_off[4];
    #pragma unroll
    for (int j = 0; j < 4; ++j) {
        int wj = w0 + j; if (wj >= WF) wj -= WF;   // w wraps within same rc (h+1)
        a_off[j] = rc * WF + wj;
    }

    float hr[4] = {0.f, 0.f, 0.f, 0.f};
    float hi[4] = {0.f, 0.f, 0.f, 0.f};

    for (int l = 0; l < LL; ++l) {
        int bl = b * LL + l;
        int base = bl * SLAB + rest;          // < 28.9M, fits int
        float4 xr = *reinterpret_cast<const float4*>(ur + base);
        float4 xi = *reinterpret_cast<const float4*>(ui + base);

        int ab = bl * ASLAB;
        float ar[4], ai[4];
        if (PRE) {
            #pragma unroll
            for (int j = 0; j < 4; ++j) {
                ar[j] = Ar[ab + a_off[j]];
                ai[j] = Ai[ab + a_off[j]];
            }
        } else {
            float dt = dts[bl];
            #pragma unroll
            for (int j = 0; j < 4; ++j) {
                float d = __expf(-nu[ab + a_off[j]] * dt);
                float s, c;
                __sincosf(th[ab + a_off[j]] * dt, &s, &c);
                ar[j] = d * c; ai[j] = d * s;
            }
        }

        float xrv[4] = {xr.x, xr.y, xr.z, xr.w};
        float xiv[4] = {xi.x, xi.y, xi.z, xi.w};
        #pragma unroll
        for (int j = 0; j < 4; ++j) {
            float nr = ar[j] * hr[j] - ai[j] * hi[j] + xrv[j];
            float ni = ar[j] * hi[j] + ai[j] * hr[j] + xiv[j];
            hr[j] = nr; hi[j] = ni;
        }

        *reinterpret_cast<float4*>(out + base) = make_float4(hr[0], hr[1], hr[2], hr[3]);
        *reinterpret_cast<float4*>(out + OUT_HALF + base) = make_float4(hi[0], hi[1], hi[2], hi[3]);
    }
}

extern "C" void kernel_launch(void* const* d_in, const int* in_sizes, int n_in,
                              void* d_out, int out_size, void* d_ws, size_t ws_size,
                              hipStream_t stream) {
    const float* nu  = (const float*)d_in[0];   // (B,L,R,C,Wf)
    const float* th  = (const float*)d_in[1];   // (B,L,R,C,Wf)
    const float* dts = (const float*)d_in[2];   // (B,L)
    const float* ur  = (const float*)d_in[3];   // (B,L,R,C,H,Wf)
    const float* ui  = (const float*)d_in[4];   // (B,L,R,C,H,Wf)
    float* out = (float*)d_out;                 // (2,B,L,R,C,H,Wf) f32

    const size_t a_elems = (size_t)BB * LL * ASLAB;          // 602112
    const bool use_ws = ws_size >= a_elems * 2 * sizeof(float);
    float* Ar = (float*)d_ws;
    float* Ai = Ar + a_elems;

    if (use_ws) {
        int na = (int)a_elems;
        a_kernel<<<(na + 255) / 256, 256, 0, stream>>>(nu, th, dts, Ar, Ai);
        scan_kernel<true><<<NTHREADS / 256, 256, 0, stream>>>(ur, ui, Ar, Ai, nu, th, dts, out);
    } else {
        scan_kernel<false><<<NTHREADS / 256, 256, 0, stream>>>(ur, ui, nullptr, nullptr, nu, th, dts, out);
    }
}